// Round 5
// baseline (143.566 us; speedup 1.0000x reference)
//
#include <hip/hip_runtime.h>
#include <stdint.h>

// (B,T,D)=(32,512,512), M=4096, N_FALSE_NEG=64, TEMP=0.1
#define T_DIM 512
#define D_DIM 512
#define M_ROWS 4096
#define NNEG 64
#define INV_TEMP 10.0f
#define SPAN 4094u        // maxval - minval = (M-2) - 0
#define MULT 1024u        // (2^16 % 4094)^2 % 4094
#define NBLK (M_ROWS / 4)

typedef float v2f __attribute__((ext_vector_type(2)));

struct U2 { uint32_t a, b; };

__host__ __device__ constexpr uint32_t rotl32(uint32_t x, uint32_t r) {
  return (x << r) | (x >> (32u - r));
}

// JAX threefry2x32 (20 rounds) — bit-exact vs reference (round 1 absmax 0.0)
__host__ __device__ constexpr U2 tf2x32(uint32_t k0, uint32_t k1,
                                        uint32_t c0, uint32_t c1) {
  uint32_t ks0 = k0, ks1 = k1, ks2 = k0 ^ k1 ^ 0x1BD11BDAu;
  uint32_t x0 = c0 + ks0, x1 = c1 + ks1;
  x0 += x1; x1 = rotl32(x1, 13); x1 ^= x0;
  x0 += x1; x1 = rotl32(x1, 15); x1 ^= x0;
  x0 += x1; x1 = rotl32(x1, 26); x1 ^= x0;
  x0 += x1; x1 = rotl32(x1, 6);  x1 ^= x0;
  x0 += ks1; x1 += ks2 + 1u;
  x0 += x1; x1 = rotl32(x1, 17); x1 ^= x0;
  x0 += x1; x1 = rotl32(x1, 29); x1 ^= x0;
  x0 += x1; x1 = rotl32(x1, 16); x1 ^= x0;
  x0 += x1; x1 = rotl32(x1, 24); x1 ^= x0;
  x0 += ks2; x1 += ks0 + 2u;
  x0 += x1; x1 = rotl32(x1, 13); x1 ^= x0;
  x0 += x1; x1 = rotl32(x1, 15); x1 ^= x0;
  x0 += x1; x1 = rotl32(x1, 26); x1 ^= x0;
  x0 += x1; x1 = rotl32(x1, 6);  x1 ^= x0;
  x0 += ks0; x1 += ks1 + 3u;
  x0 += x1; x1 = rotl32(x1, 17); x1 ^= x0;
  x0 += x1; x1 = rotl32(x1, 29); x1 ^= x0;
  x0 += x1; x1 = rotl32(x1, 16); x1 ^= x0;
  x0 += x1; x1 = rotl32(x1, 24); x1 ^= x0;
  x0 += ks1; x1 += ks2 + 4u;
  x0 += x1; x1 = rotl32(x1, 13); x1 ^= x0;
  x0 += x1; x1 = rotl32(x1, 15); x1 ^= x0;
  x0 += x1; x1 = rotl32(x1, 26); x1 ^= x0;
  x0 += x1; x1 = rotl32(x1, 6);  x1 ^= x0;
  x0 += ks2; x1 += ks0 + 5u;
  return U2{x0, x1};
}

constexpr U2 KHI = tf2x32(0u, 42u, 0u, 0u);  // split(key(42))[0]
constexpr U2 KLO = tf2x32(0u, 42u, 0u, 1u);  // split(key(42))[1]

__device__ inline uint32_t sel_index(uint32_t m, uint32_t j) {
  uint32_t pos = m * 64u + j;
  U2 h = tf2x32(KHI.a, KHI.b, 0u, pos);
  U2 l = tf2x32(KLO.a, KLO.b, 0u, pos);
  uint32_t hi = h.a ^ h.b;
  uint32_t lo = l.a ^ l.b;
  uint32_t r = ((hi % SPAN) * MULT + (lo % SPAN)) % SPAN;
  return r + (r >= m ? 1u : 0u);
}

// Kernel 1: build fp8-e4m3 normalized-enc table + sel table; zero accum.
__global__ __launch_bounds__(256) void k_norm_enc(
    const float* __restrict__ enc, const int* __restrict__ ids,
    int2* __restrict__ nenc, int* __restrict__ selTab,
    unsigned int* __restrict__ accum) {
  int lane = threadIdx.x & 63;
  int wave = threadIdx.x >> 6;
  int m = blockIdx.x * 4 + wave;

  if (blockIdx.x == 0 && threadIdx.x < 4) accum[threadIdx.x] = 0u;

  // sel precompute (threefry off contrast's hot path)
  selTab[m * 64 + lane] = (int)sel_index((uint32_t)m, (uint32_t)lane);

  int2 rc = ((const int2*)ids)[m];
  size_t base = ((size_t)rc.x * T_DIM + rc.y) * D_DIM;
  const float4* ep = (const float4*)(enc + base);
  float4 e0 = ep[2 * lane], e1 = ep[2 * lane + 1];

  float se = e0.x*e0.x + e0.y*e0.y + e0.z*e0.z + e0.w*e0.w
           + e1.x*e1.x + e1.y*e1.y + e1.z*e1.z + e1.w*e1.w;
  #pragma unroll
  for (int off = 1; off < 64; off <<= 1) se += __shfl_xor(se, off, 64);
  float inv_e = 1.0f / fmaxf(sqrtf(se), 1e-12f);

  int w0 = __builtin_amdgcn_cvt_pk_fp8_f32(e0.x * inv_e, e0.y * inv_e, 0, false);
  w0     = __builtin_amdgcn_cvt_pk_fp8_f32(e0.z * inv_e, e0.w * inv_e, w0, true);
  int w1 = __builtin_amdgcn_cvt_pk_fp8_f32(e1.x * inv_e, e1.y * inv_e, 0, false);
  w1     = __builtin_amdgcn_cvt_pk_fp8_f32(e1.z * inv_e, e1.w * inv_e, w1, true);
  nenc[m * 64 + lane] = make_int2(w0, w1);
}

// 8-elem fp8 dot vs v2f weights: 4 cvt + 1 pk_mul + 3 pk_fma + 1 add
__device__ inline float dot8_fp8v(int2 q, const v2f* pn2) {
  v2f a0 = __builtin_amdgcn_cvt_pk_f32_fp8(q.x, false);
  v2f acc = a0 * pn2[0];
  v2f a1 = __builtin_amdgcn_cvt_pk_f32_fp8(q.x, true);
  acc = __builtin_elementwise_fma(a1, pn2[1], acc);
  v2f a2 = __builtin_amdgcn_cvt_pk_f32_fp8(q.y, false);
  acc = __builtin_elementwise_fma(a2, pn2[2], acc);
  v2f a3 = __builtin_amdgcn_cvt_pk_f32_fp8(q.y, true);
  acc = __builtin_elementwise_fma(a3, pn2[3], acc);
  return acc.x + acc.y;
}

// Transpose-reduce 4 wave-wide partial dots: after this, each quad's lanes
// hold candidate (base+quad)'s full 64-lane dot. 12 shuffle-adds vs 24.
__device__ inline float reduce4(float d0, float d1, float d2, float d3, int quad) {
  d0 += __shfl_xor(d0, 16, 64); d0 += __shfl_xor(d0, 32, 64);
  d1 += __shfl_xor(d1, 16, 64); d1 += __shfl_xor(d1, 32, 64);
  d2 += __shfl_xor(d2, 16, 64); d2 += __shfl_xor(d2, 32, 64);
  d3 += __shfl_xor(d3, 16, 64); d3 += __shfl_xor(d3, 32, 64);
  float c = (quad == 0) ? d0 : (quad == 1) ? d1 : (quad == 2) ? d2 : d3;
  c += __shfl_xor(c, 1, 64);
  c += __shfl_xor(c, 2, 64);
  c += __shfl_xor(c, 4, 64);
  c += __shfl_xor(c, 8, 64);
  return c;
}

// Kernel 2: 1 wave per row; fused finalize via ticket counter.
__global__ __launch_bounds__(256) void k_contrast(
    const float* __restrict__ pred, const int* __restrict__ ids,
    const int2* __restrict__ nenc, const int* __restrict__ selTab,
    unsigned int* __restrict__ accum, float* __restrict__ out) {
  int lane = threadIdx.x & 63;
  int wave = threadIdx.x >> 6;
  int m = blockIdx.x * 4 + wave;
  int quad = lane >> 4;

  __shared__ int sel_lds[4][64];
  __shared__ float2 wred[4];
  sel_lds[wave][lane] = selTab[m * 64 + lane];

  // own p row: fp32 gather (wave-coalesced 2KB), normalize in-register
  int2 rc = ((const int2*)ids)[m];
  size_t base = ((size_t)rc.x * T_DIM + rc.y) * D_DIM;
  const float4* pp = (const float4*)(pred + base);
  float4 p0 = pp[2 * lane], p1 = pp[2 * lane + 1];
  float sp = p0.x*p0.x + p0.y*p0.y + p0.z*p0.z + p0.w*p0.w
           + p1.x*p1.x + p1.y*p1.y + p1.z*p1.z + p1.w*p1.w;
  #pragma unroll
  for (int off = 1; off < 64; off <<= 1) sp += __shfl_xor(sp, off, 64);
  float inv_p = 1.0f / fmaxf(sqrtf(sp), 1e-12f);

  v2f pn2[4];
  pn2[0] = (v2f){p0.x * inv_p, p0.y * inv_p};
  pn2[1] = (v2f){p0.z * inv_p, p0.w * inv_p};
  pn2[2] = (v2f){p1.x * inv_p, p1.y * inv_p};
  pn2[3] = (v2f){p1.z * inv_p, p1.w * inv_p};

  // sim0 against own fp8 row (quantization consistent with negatives)
  float dp = dot8_fp8v(nenc[m * 64 + lane], pn2);
  #pragma unroll
  for (int off = 1; off < 64; off <<= 1) dp += __shfl_xor(dp, off, 64);
  float s0 = dp * INV_TEMP;

  float sumexp_n = 0.0f;   // negatives only (exp(s0) added after cross-quad sum)
  float maxneg = -1e30f;

  for (int jj = 0; jj < NNEG; jj += 8) {
    int4 sa = *((const int4*)&sel_lds[wave][jj]);      // wave-uniform
    int4 sb = *((const int4*)&sel_lds[wave][jj + 4]);
    int2 q0 = nenc[(size_t)sa.x * 64 + lane];
    int2 q1 = nenc[(size_t)sa.y * 64 + lane];
    int2 q2 = nenc[(size_t)sa.z * 64 + lane];
    int2 q3 = nenc[(size_t)sa.w * 64 + lane];
    int2 q4 = nenc[(size_t)sb.x * 64 + lane];
    int2 q5 = nenc[(size_t)sb.y * 64 + lane];
    int2 q6 = nenc[(size_t)sb.z * 64 + lane];
    int2 q7 = nenc[(size_t)sb.w * 64 + lane];
    float d0 = dot8_fp8v(q0, pn2), d1 = dot8_fp8v(q1, pn2);
    float d2 = dot8_fp8v(q2, pn2), d3 = dot8_fp8v(q3, pn2);
    float d4 = dot8_fp8v(q4, pn2), d5 = dot8_fp8v(q5, pn2);
    float d6 = dot8_fp8v(q6, pn2), d7 = dot8_fp8v(q7, pn2);
    // lane's quad owns candidates jj+quad and jj+4+quad
    float c1 = reduce4(d0, d1, d2, d3, quad) * INV_TEMP;
    float c2 = reduce4(d4, d5, d6, d7, quad) * INV_TEMP;
    maxneg = fmaxf(maxneg, fmaxf(c1, c2));
    sumexp_n += __expf(c1) + __expf(c2);
  }
  // cross-quad combine (lanes within a quad identical)
  sumexp_n += __shfl_xor(sumexp_n, 16, 64);
  sumexp_n += __shfl_xor(sumexp_n, 32, 64);
  maxneg = fmaxf(maxneg, __shfl_xor(maxneg, 16, 64));
  maxneg = fmaxf(maxneg, __shfl_xor(maxneg, 32, 64));

  if (lane == 0) {
    float lse = logf(sumexp_n + __expf(s0));
    wred[wave] = make_float2(lse - s0, (s0 >= maxneg) ? 1.0f : 0.0f);
  }
  __syncthreads();
  if (threadIdx.x == 0) {
    float l = 0.0f, a = 0.0f;
    #pragma unroll
    for (int w = 0; w < 4; ++w) { l += wred[w].x; a += wred[w].y; }
    float* facc = (float*)accum;
    atomicAdd(&facc[0], l);
    atomicAdd(&facc[1], a);
    __threadfence();
    unsigned int old = atomicAdd(&accum[2], 1u);
    if (old == NBLK - 1) {  // last block: finalize
      float ll = atomicAdd(&facc[0], 0.0f);  // L2-coherent read
      float aa = atomicAdd(&facc[1], 0.0f);
      out[0] = ll * (1.0f / M_ROWS);
      out[1] = aa * (1.0f / M_ROWS);
    }
  }
}

extern "C" void kernel_launch(void* const* d_in, const int* in_sizes, int n_in,
                              void* d_out, int out_size, void* d_ws, size_t ws_size,
                              hipStream_t stream) {
  const float* pred = (const float*)d_in[0];
  const float* enc  = (const float*)d_in[1];
  const int*   ids  = (const int*)d_in[2];
  float* out = (float*)d_out;

  // ws: nenc fp8 (2 MB) | selTab (1 MB) | accum[4] (loss, acc, ticket, pad)
  int2* nenc = (int2*)d_ws;
  int* selTab = (int*)(nenc + (size_t)M_ROWS * 64);
  unsigned int* accum = (unsigned int*)(selTab + (size_t)M_ROWS * 64);

  k_norm_enc<<<NBLK, 256, 0, stream>>>(enc, ids, nenc, selTab, accum);
  k_contrast<<<NBLK, 256, 0, stream>>>(pred, ids, nenc, selTab, accum, out);
}

// Round 6
// 115.857 us; speedup vs baseline: 1.2392x; 1.2392x over previous
//
#include <hip/hip_runtime.h>
#include <stdint.h>

// (B,T,D)=(32,512,512), M=4096, N_FALSE_NEG=64, TEMP=0.1
#define T_DIM 512
#define D_DIM 512
#define M_ROWS 4096
#define NNEG 64
#define INV_TEMP 10.0f
#define SPAN 4094u        // maxval - minval = (M-2) - 0
#define MULT 1024u        // (2^16 % 4094)^2 % 4094
#define NBLK (M_ROWS / 4)

typedef float v2f __attribute__((ext_vector_type(2)));

struct U2 { uint32_t a, b; };

__host__ __device__ constexpr uint32_t rotl32(uint32_t x, uint32_t r) {
  return (x << r) | (x >> (32u - r));
}

// JAX threefry2x32 (20 rounds) — bit-exact vs reference (round 1 absmax 0.0)
__host__ __device__ constexpr U2 tf2x32(uint32_t k0, uint32_t k1,
                                        uint32_t c0, uint32_t c1) {
  uint32_t ks0 = k0, ks1 = k1, ks2 = k0 ^ k1 ^ 0x1BD11BDAu;
  uint32_t x0 = c0 + ks0, x1 = c1 + ks1;
  x0 += x1; x1 = rotl32(x1, 13); x1 ^= x0;
  x0 += x1; x1 = rotl32(x1, 15); x1 ^= x0;
  x0 += x1; x1 = rotl32(x1, 26); x1 ^= x0;
  x0 += x1; x1 = rotl32(x1, 6);  x1 ^= x0;
  x0 += ks1; x1 += ks2 + 1u;
  x0 += x1; x1 = rotl32(x1, 17); x1 ^= x0;
  x0 += x1; x1 = rotl32(x1, 29); x1 ^= x0;
  x0 += x1; x1 = rotl32(x1, 16); x1 ^= x0;
  x0 += x1; x1 = rotl32(x1, 24); x1 ^= x0;
  x0 += ks2; x1 += ks0 + 2u;
  x0 += x1; x1 = rotl32(x1, 13); x1 ^= x0;
  x0 += x1; x1 = rotl32(x1, 15); x1 ^= x0;
  x0 += x1; x1 = rotl32(x1, 26); x1 ^= x0;
  x0 += x1; x1 = rotl32(x1, 6);  x1 ^= x0;
  x0 += ks0; x1 += ks1 + 3u;
  x0 += x1; x1 = rotl32(x1, 17); x1 ^= x0;
  x0 += x1; x1 = rotl32(x1, 29); x1 ^= x0;
  x0 += x1; x1 = rotl32(x1, 16); x1 ^= x0;
  x0 += x1; x1 = rotl32(x1, 24); x1 ^= x0;
  x0 += ks1; x1 += ks2 + 4u;
  x0 += x1; x1 = rotl32(x1, 13); x1 ^= x0;
  x0 += x1; x1 = rotl32(x1, 15); x1 ^= x0;
  x0 += x1; x1 = rotl32(x1, 26); x1 ^= x0;
  x0 += x1; x1 = rotl32(x1, 6);  x1 ^= x0;
  x0 += ks2; x1 += ks0 + 5u;
  return U2{x0, x1};
}

constexpr U2 KHI = tf2x32(0u, 42u, 0u, 0u);  // split(key(42))[0]
constexpr U2 KLO = tf2x32(0u, 42u, 0u, 1u);  // split(key(42))[1]

__device__ inline uint32_t sel_index(uint32_t m, uint32_t j) {
  uint32_t pos = m * 64u + j;
  U2 h = tf2x32(KHI.a, KHI.b, 0u, pos);
  U2 l = tf2x32(KLO.a, KLO.b, 0u, pos);
  uint32_t hi = h.a ^ h.b;
  uint32_t lo = l.a ^ l.b;
  uint32_t r = ((hi % SPAN) * MULT + (lo % SPAN)) % SPAN;
  return r + (r >= m ? 1u : 0u);
}

// Kernel 1: fp8-e4m3 normalized-enc table (512 B/row) + sel table.
__global__ __launch_bounds__(256) void k_norm_enc(
    const float* __restrict__ enc, const int* __restrict__ ids,
    int2* __restrict__ nenc, int* __restrict__ selTab) {
  int lane = threadIdx.x & 63;
  int wave = threadIdx.x >> 6;
  int m = blockIdx.x * 4 + wave;

  // threefry moved off contrast's hot path
  selTab[m * 64 + lane] = (int)sel_index((uint32_t)m, (uint32_t)lane);

  int2 rc = ((const int2*)ids)[m];
  size_t base = ((size_t)rc.x * T_DIM + rc.y) * D_DIM;
  const float4* ep = (const float4*)(enc + base);
  float4 e0 = ep[2 * lane], e1 = ep[2 * lane + 1];

  float se = e0.x*e0.x + e0.y*e0.y + e0.z*e0.z + e0.w*e0.w
           + e1.x*e1.x + e1.y*e1.y + e1.z*e1.z + e1.w*e1.w;
  #pragma unroll
  for (int off = 1; off < 64; off <<= 1) se += __shfl_xor(se, off, 64);
  float inv_e = 1.0f / fmaxf(sqrtf(se), 1e-12f);

  int w0 = __builtin_amdgcn_cvt_pk_fp8_f32(e0.x * inv_e, e0.y * inv_e, 0, false);
  w0     = __builtin_amdgcn_cvt_pk_fp8_f32(e0.z * inv_e, e0.w * inv_e, w0, true);
  int w1 = __builtin_amdgcn_cvt_pk_fp8_f32(e1.x * inv_e, e1.y * inv_e, 0, false);
  w1     = __builtin_amdgcn_cvt_pk_fp8_f32(e1.z * inv_e, e1.w * inv_e, w1, true);
  nenc[m * 64 + lane] = make_int2(w0, w1);
}

// 8-elem fp8 dot vs v2f weights: 4 cvt + 1 pk_mul + 3 pk_fma + 1 add
__device__ inline float dot8_fp8v(int2 q, const v2f* pn2) {
  v2f a0 = __builtin_amdgcn_cvt_pk_f32_fp8(q.x, false);
  v2f acc = a0 * pn2[0];
  v2f a1 = __builtin_amdgcn_cvt_pk_f32_fp8(q.x, true);
  acc = __builtin_elementwise_fma(a1, pn2[1], acc);
  v2f a2 = __builtin_amdgcn_cvt_pk_f32_fp8(q.y, false);
  acc = __builtin_elementwise_fma(a2, pn2[2], acc);
  v2f a3 = __builtin_amdgcn_cvt_pk_f32_fp8(q.y, true);
  acc = __builtin_elementwise_fma(a3, pn2[3], acc);
  return acc.x + acc.y;
}

// Kernel 2: 1 wave per row (round-4 proven structure: jj+=4, 4 independent
// 6-step butterflies, unshifted exp, block partials, NO atomics/fences).
__global__ __launch_bounds__(256) void k_contrast(
    const float* __restrict__ pred, const int* __restrict__ ids,
    const int2* __restrict__ nenc, const int* __restrict__ selTab,
    float2* __restrict__ partials) {
  int lane = threadIdx.x & 63;
  int wave = threadIdx.x >> 6;
  int m = blockIdx.x * 4 + wave;

  __shared__ int sel_lds[4][64];
  __shared__ float2 wred[4];
  sel_lds[wave][lane] = selTab[m * 64 + lane];   // coalesced; own-wave use only

  // own p row: fp32 gather (wave-coalesced 2KB), normalize in-register
  int2 rc = ((const int2*)ids)[m];
  size_t base = ((size_t)rc.x * T_DIM + rc.y) * D_DIM;
  const float4* pp = (const float4*)(pred + base);
  float4 p0 = pp[2 * lane], p1 = pp[2 * lane + 1];
  float sp = p0.x*p0.x + p0.y*p0.y + p0.z*p0.z + p0.w*p0.w
           + p1.x*p1.x + p1.y*p1.y + p1.z*p1.z + p1.w*p1.w;
  #pragma unroll
  for (int off = 1; off < 64; off <<= 1) sp += __shfl_xor(sp, off, 64);
  float inv_p = 1.0f / fmaxf(sqrtf(sp), 1e-12f);

  v2f pn2[4];
  pn2[0] = (v2f){p0.x * inv_p, p0.y * inv_p};
  pn2[1] = (v2f){p0.z * inv_p, p0.w * inv_p};
  pn2[2] = (v2f){p1.x * inv_p, p1.y * inv_p};
  pn2[3] = (v2f){p1.z * inv_p, p1.w * inv_p};

  // sim0 against own fp8 row (quantization consistent with negatives)
  float dp = dot8_fp8v(nenc[m * 64 + lane], pn2);
  #pragma unroll
  for (int off = 1; off < 64; off <<= 1) dp += __shfl_xor(dp, off, 64);
  float s0 = dp * INV_TEMP;

  float sumexp = __expf(s0);
  float maxneg = -1e30f;

  for (int jj = 0; jj < NNEG; jj += 4) {
    int4 s4 = *((const int4*)&sel_lds[wave][jj]);  // wave-uniform broadcast
    int2 q0 = nenc[(size_t)s4.x * 64 + lane];
    int2 q1 = nenc[(size_t)s4.y * 64 + lane];
    int2 q2 = nenc[(size_t)s4.z * 64 + lane];
    int2 q3 = nenc[(size_t)s4.w * 64 + lane];
    float d0 = dot8_fp8v(q0, pn2);
    float d1 = dot8_fp8v(q1, pn2);
    float d2 = dot8_fp8v(q2, pn2);
    float d3 = dot8_fp8v(q3, pn2);
    #pragma unroll
    for (int off = 1; off < 64; off <<= 1) {  // 4 independent butterflies
      d0 += __shfl_xor(d0, off, 64);
      d1 += __shfl_xor(d1, off, 64);
      d2 += __shfl_xor(d2, off, 64);
      d3 += __shfl_xor(d3, off, 64);
    }
    float s_0 = d0 * INV_TEMP, s_1 = d1 * INV_TEMP;
    float s_2 = d2 * INV_TEMP, s_3 = d3 * INV_TEMP;
    maxneg = fmaxf(fmaxf(fmaxf(maxneg, s_0), fmaxf(s_1, s_2)), s_3);
    sumexp += __expf(s_0) + __expf(s_1) + __expf(s_2) + __expf(s_3);
  }

  if (lane == 0) {
    float lse = logf(sumexp);
    wred[wave] = make_float2(lse - s0, (s0 >= maxneg) ? 1.0f : 0.0f);
  }
  __syncthreads();
  if (threadIdx.x == 0) {
    float l = 0.0f, a = 0.0f;
    #pragma unroll
    for (int w = 0; w < 4; ++w) { l += wred[w].x; a += wred[w].y; }
    partials[blockIdx.x] = make_float2(l, a);
  }
}

// Kernel 3: reduce 1024 block partials -> (loss, acc)
__global__ __launch_bounds__(256) void k_finalize(
    const float2* __restrict__ partials, float* __restrict__ out) {
  int t = threadIdx.x;
  float l = 0.0f, a = 0.0f;
  #pragma unroll
  for (int i = 0; i < 4; ++i) {
    float2 v = partials[t + 256 * i];
    l += v.x; a += v.y;
  }
  #pragma unroll
  for (int off = 1; off < 64; off <<= 1) {
    l += __shfl_xor(l, off, 64);
    a += __shfl_xor(a, off, 64);
  }
  __shared__ float2 wred[4];
  if ((t & 63) == 0) wred[t >> 6] = make_float2(l, a);
  __syncthreads();
  if (t == 0) {
    out[0] = (wred[0].x + wred[1].x + wred[2].x + wred[3].x) * (1.0f / M_ROWS);
    out[1] = (wred[0].y + wred[1].y + wred[2].y + wred[3].y) * (1.0f / M_ROWS);
  }
}

extern "C" void kernel_launch(void* const* d_in, const int* in_sizes, int n_in,
                              void* d_out, int out_size, void* d_ws, size_t ws_size,
                              hipStream_t stream) {
  const float* pred = (const float*)d_in[0];
  const float* enc  = (const float*)d_in[1];
  const int*   ids  = (const int*)d_in[2];
  float* out = (float*)d_out;

  // ws: nenc fp8 (2 MB) | selTab (1 MB) | partials (1024 float2)
  int2* nenc = (int2*)d_ws;
  int* selTab = (int*)(nenc + (size_t)M_ROWS * 64);
  float2* partials = (float2*)(selTab + (size_t)M_ROWS * 64);

  k_norm_enc<<<NBLK, 256, 0, stream>>>(enc, ids, nenc, selTab);
  k_contrast<<<NBLK, 256, 0, stream>>>(pred, ids, nenc, selTab, partials);
  k_finalize<<<1, 256, 0, stream>>>(partials, out);
}

// Round 7
// 109.663 us; speedup vs baseline: 1.3092x; 1.0565x over previous
//
#include <hip/hip_runtime.h>
#include <stdint.h>

// (B,T,D)=(32,512,512), M=4096, N_FALSE_NEG=64, TEMP=0.1
#define T_DIM 512
#define D_DIM 512
#define M_ROWS 4096
#define NNEG 64
#define INV_TEMP 10.0f
#define SPAN 4094u        // maxval - minval = (M-2) - 0
#define MULT 1024u        // (2^16 % 4094)^2 % 4094
#define NBLK (M_ROWS / 4)

typedef float v2f __attribute__((ext_vector_type(2)));

struct U2 { uint32_t a, b; };

__host__ __device__ constexpr uint32_t rotl32(uint32_t x, uint32_t r) {
  return (x << r) | (x >> (32u - r));
}

// JAX threefry2x32 (20 rounds) — bit-exact vs reference (round 1 absmax 0.0)
__host__ __device__ constexpr U2 tf2x32(uint32_t k0, uint32_t k1,
                                        uint32_t c0, uint32_t c1) {
  uint32_t ks0 = k0, ks1 = k1, ks2 = k0 ^ k1 ^ 0x1BD11BDAu;
  uint32_t x0 = c0 + ks0, x1 = c1 + ks1;
  x0 += x1; x1 = rotl32(x1, 13); x1 ^= x0;
  x0 += x1; x1 = rotl32(x1, 15); x1 ^= x0;
  x0 += x1; x1 = rotl32(x1, 26); x1 ^= x0;
  x0 += x1; x1 = rotl32(x1, 6);  x1 ^= x0;
  x0 += ks1; x1 += ks2 + 1u;
  x0 += x1; x1 = rotl32(x1, 17); x1 ^= x0;
  x0 += x1; x1 = rotl32(x1, 29); x1 ^= x0;
  x0 += x1; x1 = rotl32(x1, 16); x1 ^= x0;
  x0 += x1; x1 = rotl32(x1, 24); x1 ^= x0;
  x0 += ks2; x1 += ks0 + 2u;
  x0 += x1; x1 = rotl32(x1, 13); x1 ^= x0;
  x0 += x1; x1 = rotl32(x1, 15); x1 ^= x0;
  x0 += x1; x1 = rotl32(x1, 26); x1 ^= x0;
  x0 += x1; x1 = rotl32(x1, 6);  x1 ^= x0;
  x0 += ks0; x1 += ks1 + 3u;
  x0 += x1; x1 = rotl32(x1, 17); x1 ^= x0;
  x0 += x1; x1 = rotl32(x1, 29); x1 ^= x0;
  x0 += x1; x1 = rotl32(x1, 16); x1 ^= x0;
  x0 += x1; x1 = rotl32(x1, 24); x1 ^= x0;
  x0 += ks1; x1 += ks2 + 4u;
  x0 += x1; x1 = rotl32(x1, 13); x1 ^= x0;
  x0 += x1; x1 = rotl32(x1, 15); x1 ^= x0;
  x0 += x1; x1 = rotl32(x1, 26); x1 ^= x0;
  x0 += x1; x1 = rotl32(x1, 6);  x1 ^= x0;
  x0 += ks2; x1 += ks0 + 5u;
  return U2{x0, x1};
}

constexpr U2 KHI = tf2x32(0u, 42u, 0u, 0u);  // split(key(42))[0]
constexpr U2 KLO = tf2x32(0u, 42u, 0u, 1u);  // split(key(42))[1]

__device__ inline uint32_t sel_index(uint32_t m, uint32_t j) {
  uint32_t pos = m * 64u + j;
  U2 h = tf2x32(KHI.a, KHI.b, 0u, pos);
  U2 l = tf2x32(KLO.a, KLO.b, 0u, pos);
  uint32_t hi = h.a ^ h.b;
  uint32_t lo = l.a ^ l.b;
  uint32_t r = ((hi % SPAN) * MULT + (lo % SPAN)) % SPAN;
  return r + (r >= m ? 1u : 0u);
}

// Kernel 1: fp8-e4m3 normalized-enc table (512 B/row) + sel table.
__global__ __launch_bounds__(256) void k_norm_enc(
    const float* __restrict__ enc, const int* __restrict__ ids,
    int2* __restrict__ nenc, int* __restrict__ selTab) {
  int lane = threadIdx.x & 63;
  int wave = threadIdx.x >> 6;
  int m = blockIdx.x * 4 + wave;

  // threefry off contrast's hot path
  selTab[m * 64 + lane] = (int)sel_index((uint32_t)m, (uint32_t)lane);

  int2 rc = ((const int2*)ids)[m];
  size_t base = ((size_t)rc.x * T_DIM + rc.y) * D_DIM;
  const float4* ep = (const float4*)(enc + base);
  float4 e0 = ep[2 * lane], e1 = ep[2 * lane + 1];

  float se = e0.x*e0.x + e0.y*e0.y + e0.z*e0.z + e0.w*e0.w
           + e1.x*e1.x + e1.y*e1.y + e1.z*e1.z + e1.w*e1.w;
  #pragma unroll
  for (int off = 1; off < 64; off <<= 1) se += __shfl_xor(se, off, 64);
  float inv_e = 1.0f / fmaxf(sqrtf(se), 1e-12f);

  int w0 = __builtin_amdgcn_cvt_pk_fp8_f32(e0.x * inv_e, e0.y * inv_e, 0, false);
  w0     = __builtin_amdgcn_cvt_pk_fp8_f32(e0.z * inv_e, e0.w * inv_e, w0, true);
  int w1 = __builtin_amdgcn_cvt_pk_fp8_f32(e1.x * inv_e, e1.y * inv_e, 0, false);
  w1     = __builtin_amdgcn_cvt_pk_fp8_f32(e1.z * inv_e, e1.w * inv_e, w1, true);
  nenc[m * 64 + lane] = make_int2(w0, w1);
}

// 8-elem fp8 dot vs v2f weights: 4 cvt + 1 pk_mul + 3 pk_fma + 1 add
__device__ inline float dot8_fp8v(int2 q, const v2f* pn2) {
  v2f a0 = __builtin_amdgcn_cvt_pk_f32_fp8(q.x, false);
  v2f acc = a0 * pn2[0];
  v2f a1 = __builtin_amdgcn_cvt_pk_f32_fp8(q.x, true);
  acc = __builtin_elementwise_fma(a1, pn2[1], acc);
  v2f a2 = __builtin_amdgcn_cvt_pk_f32_fp8(q.y, false);
  acc = __builtin_elementwise_fma(a2, pn2[2], acc);
  v2f a3 = __builtin_amdgcn_cvt_pk_f32_fp8(q.y, true);
  acc = __builtin_elementwise_fma(a3, pn2[3], acc);
  return acc.x + acc.y;
}

// Transpose-reduce 4 wave-wide partial dots: 12 shuffle-adds (vs 24 for four
// butterflies); each quad ends up owning one candidate's full dot.
// Correctness-validated in round 5 (absmax 0.0).
__device__ inline float reduce4(float d0, float d1, float d2, float d3, int quad) {
  d0 += __shfl_xor(d0, 16, 64); d0 += __shfl_xor(d0, 32, 64);
  d1 += __shfl_xor(d1, 16, 64); d1 += __shfl_xor(d1, 32, 64);
  d2 += __shfl_xor(d2, 16, 64); d2 += __shfl_xor(d2, 32, 64);
  d3 += __shfl_xor(d3, 16, 64); d3 += __shfl_xor(d3, 32, 64);
  float c = (quad == 0) ? d0 : (quad == 1) ? d1 : (quad == 2) ? d2 : d3;
  c += __shfl_xor(c, 1, 64);
  c += __shfl_xor(c, 2, 64);
  c += __shfl_xor(c, 4, 64);
  c += __shfl_xor(c, 8, 64);
  return c;
}

// Kernel 2: 1 wave per row; jj+=8 pipelining; transpose-reduce; block
// partials, NO atomics/fences (round-5 lesson: per-block device fences
// storm the L2).
__global__ __launch_bounds__(256) void k_contrast(
    const float* __restrict__ pred, const int* __restrict__ ids,
    const int2* __restrict__ nenc, const int* __restrict__ selTab,
    float2* __restrict__ partials) {
  int lane = threadIdx.x & 63;
  int wave = threadIdx.x >> 6;
  int m = blockIdx.x * 4 + wave;
  int quad = lane >> 4;

  __shared__ int sel_lds[4][64];
  __shared__ float2 wred[4];
  sel_lds[wave][lane] = selTab[m * 64 + lane];   // coalesced; own-wave use only

  // own p row: fp32 gather (wave-coalesced 2KB), normalize in-register
  int2 rc = ((const int2*)ids)[m];
  size_t base = ((size_t)rc.x * T_DIM + rc.y) * D_DIM;
  const float4* pp = (const float4*)(pred + base);
  float4 p0 = pp[2 * lane], p1 = pp[2 * lane + 1];
  float sp = p0.x*p0.x + p0.y*p0.y + p0.z*p0.z + p0.w*p0.w
           + p1.x*p1.x + p1.y*p1.y + p1.z*p1.z + p1.w*p1.w;
  #pragma unroll
  for (int off = 1; off < 64; off <<= 1) sp += __shfl_xor(sp, off, 64);
  float inv_p = 1.0f / fmaxf(sqrtf(sp), 1e-12f);

  v2f pn2[4];
  pn2[0] = (v2f){p0.x * inv_p, p0.y * inv_p};
  pn2[1] = (v2f){p0.z * inv_p, p0.w * inv_p};
  pn2[2] = (v2f){p1.x * inv_p, p1.y * inv_p};
  pn2[3] = (v2f){p1.z * inv_p, p1.w * inv_p};

  // sim0 against own fp8 row (quantization consistent with negatives)
  float dp = dot8_fp8v(nenc[m * 64 + lane], pn2);
  #pragma unroll
  for (int off = 1; off < 64; off <<= 1) dp += __shfl_xor(dp, off, 64);
  float s0 = dp * INV_TEMP;

  float sumexp_n = 0.0f;   // negatives only; exp(s0) added after cross-quad sum
  float maxneg = -1e30f;

  for (int jj = 0; jj < NNEG; jj += 8) {
    int4 sa = *((const int4*)&sel_lds[wave][jj]);      // wave-uniform
    int4 sb = *((const int4*)&sel_lds[wave][jj + 4]);
    int2 q0 = nenc[(size_t)sa.x * 64 + lane];
    int2 q1 = nenc[(size_t)sa.y * 64 + lane];
    int2 q2 = nenc[(size_t)sa.z * 64 + lane];
    int2 q3 = nenc[(size_t)sa.w * 64 + lane];
    int2 q4 = nenc[(size_t)sb.x * 64 + lane];
    int2 q5 = nenc[(size_t)sb.y * 64 + lane];
    int2 q6 = nenc[(size_t)sb.z * 64 + lane];
    int2 q7 = nenc[(size_t)sb.w * 64 + lane];
    float d0 = dot8_fp8v(q0, pn2), d1 = dot8_fp8v(q1, pn2);
    float d2 = dot8_fp8v(q2, pn2), d3 = dot8_fp8v(q3, pn2);
    float d4 = dot8_fp8v(q4, pn2), d5 = dot8_fp8v(q5, pn2);
    float d6 = dot8_fp8v(q6, pn2), d7 = dot8_fp8v(q7, pn2);
    // lane's quad owns candidates jj+quad and jj+4+quad
    float c1 = reduce4(d0, d1, d2, d3, quad) * INV_TEMP;
    float c2 = reduce4(d4, d5, d6, d7, quad) * INV_TEMP;
    maxneg = fmaxf(maxneg, fmaxf(c1, c2));
    sumexp_n += __expf(c1) + __expf(c2);
  }
  // cross-quad combine (lanes within a quad identical)
  sumexp_n += __shfl_xor(sumexp_n, 16, 64);
  sumexp_n += __shfl_xor(sumexp_n, 32, 64);
  maxneg = fmaxf(maxneg, __shfl_xor(maxneg, 16, 64));
  maxneg = fmaxf(maxneg, __shfl_xor(maxneg, 32, 64));

  if (lane == 0) {
    float lse = logf(sumexp_n + __expf(s0));
    wred[wave] = make_float2(lse - s0, (s0 >= maxneg) ? 1.0f : 0.0f);
  }
  __syncthreads();
  if (threadIdx.x == 0) {
    float l = 0.0f, a = 0.0f;
    #pragma unroll
    for (int w = 0; w < 4; ++w) { l += wred[w].x; a += wred[w].y; }
    partials[blockIdx.x] = make_float2(l, a);
  }
}

// Kernel 3: reduce 1024 block partials -> (loss, acc)
__global__ __launch_bounds__(256) void k_finalize(
    const float2* __restrict__ partials, float* __restrict__ out) {
  int t = threadIdx.x;
  float l = 0.0f, a = 0.0f;
  #pragma unroll
  for (int i = 0; i < 4; ++i) {
    float2 v = partials[t + 256 * i];
    l += v.x; a += v.y;
  }
  #pragma unroll
  for (int off = 1; off < 64; off <<= 1) {
    l += __shfl_xor(l, off, 64);
    a += __shfl_xor(a, off, 64);
  }
  __shared__ float2 wred[4];
  if ((t & 63) == 0) wred[t >> 6] = make_float2(l, a);
  __syncthreads();
  if (t == 0) {
    out[0] = (wred[0].x + wred[1].x + wred[2].x + wred[3].x) * (1.0f / M_ROWS);
    out[1] = (wred[0].y + wred[1].y + wred[2].y + wred[3].y) * (1.0f / M_ROWS);
  }
}

extern "C" void kernel_launch(void* const* d_in, const int* in_sizes, int n_in,
                              void* d_out, int out_size, void* d_ws, size_t ws_size,
                              hipStream_t stream) {
  const float* pred = (const float*)d_in[0];
  const float* enc  = (const float*)d_in[1];
  const int*   ids  = (const int*)d_in[2];
  float* out = (float*)d_out;

  // ws: nenc fp8 (2 MB) | selTab (1 MB) | partials (1024 float2)
  int2* nenc = (int2*)d_ws;
  int* selTab = (int*)(nenc + (size_t)M_ROWS * 64);
  float2* partials = (float2*)(selTab + (size_t)M_ROWS * 64);

  k_norm_enc<<<NBLK, 256, 0, stream>>>(enc, ids, nenc, selTab);
  k_contrast<<<NBLK, 256, 0, stream>>>(pred, ids, nenc, selTab, partials);
  k_finalize<<<1, 256, 0, stream>>>(partials, out);
}